// Round 2
// baseline (302.552 us; speedup 1.0000x reference)
//
#include <hip/hip_runtime.h>

#define N_IMG 32
#define C_CH  128
#define H_DIM 96
#define W_DIM 96
#define HW    (H_DIM*W_DIM)   // 9216
#define K_CL  64
#define EPSF  1e-12f

#define TPB   256
#define TP    256             // pixels per block
#define SP    32              // pixels per subtile
#define NSUB  (TP/SP)         // 8
#define XP    132             // x_lds pitch (floats), 16B-aligned rows
#define WP    132             // w_lds pitch
#define SPP   68              // soft_lds pitch

// ws layout (in floats)
#define WS_VLAD 0
#define WS_ASUM (N_IMG*K_CL*C_CH)          // 262144
#define WS_IMG  (WS_ASUM + N_IMG*K_CL)     // 264192
#define WS_TOT  (WS_IMG + N_IMG)           // 264224

__global__ void k_zero(float* __restrict__ ws) {
    int i = blockIdx.x * blockDim.x + threadIdx.x;
    if (i < WS_TOT) ws[i] = 0.f;
}

__global__ __launch_bounds__(TPB, 2) void k_fused(
    const float* __restrict__ x, const float* __restrict__ conv_w,
    float* __restrict__ vlad, float* __restrict__ asum)
{
    __shared__ __align__(16) float w_lds[K_CL * WP];   // 33792 B
    __shared__ __align__(16) float x_lds[SP * XP];     // 16896 B
    __shared__ __align__(16) float s_lds[SP * SPP];    //  8704 B
    __shared__ float red[8 * 32];
    __shared__ float invn[SP];

    const int t   = threadIdx.x;
    const int bpi = HW / TP;                 // 36 blocks per image
    const int n   = blockIdx.x / bpi;
    const int pb  = (blockIdx.x % bpi) * TP;

    // stage conv_w [k][c] -> w_lds
    #pragma unroll
    for (int r = 0; r < (K_CL * C_CH) / TPB; ++r) {
        int i = t + TPB * r;
        w_lds[(i >> 7) * WP + (i & 127)] = conv_w[i];
    }

    float acc[32];
    #pragma unroll
    for (int i = 0; i < 32; ++i) acc[i] = 0.f;
    float asum_acc = 0.f;

    const int cq   = t & 127;   // phase d: this thread's channel
    const int kh   = t >> 7;    // phase d: k half (0/1)
    const int pa   = t & 31;    // phase a: pixel
    const int crow = t >> 5;    // phase a: channel row 0..7
    const int pb8  = t >> 3;    // phase b: pixel 0..31
    const int kg   = t & 7;     // phase b: k group 0..7

    const float* xb = x + (size_t)n * (size_t)(C_CH) * (size_t)HW;

    for (int st = 0; st < NSUB; ++st) {
        const int p0 = pb + st * SP;
        __syncthreads();   // protect LDS tiles from previous iteration readers

        // ---- phase a: stage raw x tile (coalesced over pixels) ----
        #pragma unroll
        for (int i = 0; i < 16; ++i) {
            int c = crow + 8 * i;
            x_lds[pa * XP + c] = xb[(size_t)c * HW + p0 + pa];
        }
        __syncthreads();

        // ---- per-pixel sum of squares ----
        {
            float ss = 0.f;
            #pragma unroll
            for (int i = 0; i < 16; ++i) {
                float v = x_lds[pa * XP + crow * 16 + i];
                ss += v * v;
            }
            red[crow * 32 + pa] = ss;
        }
        __syncthreads();
        if (t < SP) {
            float ss = 0.f;
            #pragma unroll
            for (int i = 0; i < 8; ++i) ss += red[i * 32 + t];
            invn[t] = 1.f / fmaxf(sqrtf(ss), EPSF);
        }
        __syncthreads();
        {
            float s = invn[pa];
            #pragma unroll
            for (int i = 0; i < 16; ++i)
                x_lds[pa * XP + crow + 8 * i] *= s;
        }
        __syncthreads();

        // ---- phase b: logits (k = kg + 8*j) ----
        float lg[8];
        #pragma unroll
        for (int j = 0; j < 8; ++j) lg[j] = 0.f;
        for (int c = 0; c < C_CH; c += 4) {
            float4 xv = *(const float4*)&x_lds[pb8 * XP + c];
            #pragma unroll
            for (int j = 0; j < 8; ++j) {
                int k = kg + 8 * j;
                float4 wv = *(const float4*)&w_lds[k * WP + c];
                lg[j] += wv.x * xv.x + wv.y * xv.y + wv.z * xv.z + wv.w * xv.w;
            }
        }

        // ---- softmax over 64 clusters: 8 in-thread x 8 lanes ----
        float m = lg[0];
        #pragma unroll
        for (int j = 1; j < 8; ++j) m = fmaxf(m, lg[j]);
        m = fmaxf(m, __shfl_xor(m, 1));
        m = fmaxf(m, __shfl_xor(m, 2));
        m = fmaxf(m, __shfl_xor(m, 4));
        float e[8];
        float sm = 0.f;
        #pragma unroll
        for (int j = 0; j < 8; ++j) { e[j] = __expf(lg[j] - m); sm += e[j]; }
        sm += __shfl_xor(sm, 1);
        sm += __shfl_xor(sm, 2);
        sm += __shfl_xor(sm, 4);
        float is = 1.f / sm;
        #pragma unroll
        for (int j = 0; j < 8; ++j)
            s_lds[pb8 * SPP + kg + 8 * j] = e[j] * is;
        __syncthreads();

        // ---- asum partials (wave 0 only, cheap) ----
        if (t < K_CL) {
            #pragma unroll
            for (int p = 0; p < SP; ++p) asum_acc += s_lds[p * SPP + t];
        }

        // ---- phase d: vlad outer-product accumulation ----
        for (int p = 0; p < SP; ++p) {
            float xv = x_lds[p * XP + cq];
            #pragma unroll
            for (int jj = 0; jj < 8; ++jj) {
                float4 s4 = *(const float4*)&s_lds[p * SPP + kh * 32 + 4 * jj];
                acc[4 * jj + 0] += s4.x * xv;
                acc[4 * jj + 1] += s4.y * xv;
                acc[4 * jj + 2] += s4.z * xv;
                acc[4 * jj + 3] += s4.w * xv;
            }
        }
    }

    // ---- flush partials ----
    float* vrow = vlad + ((size_t)n * K_CL + kh * 32) * C_CH + cq;
    #pragma unroll
    for (int kk = 0; kk < 32; ++kk)
        atomicAdd(vrow + (size_t)kk * C_CH, acc[kk]);
    if (t < K_CL) atomicAdd(asum + n * K_CL + t, asum_acc);
}

// per-(n,k) row: subtract asum*centroid, intra-normalize, accumulate image norm^2
__global__ void k_rows(float* __restrict__ vlad, const float* __restrict__ asum,
                       const float* __restrict__ cent, float* __restrict__ imgss)
{
    const int bx = blockIdx.x;            // n*64 + k
    const int n = bx >> 6, k = bx & 63;
    const int c = threadIdx.x;            // 128 threads
    float a = asum[n * K_CL + k];
    size_t idx = ((size_t)n * K_CL + k) * C_CH + c;
    float v = vlad[idx] - a * cent[k * C_CH + c];
    float ss = v * v;
    #pragma unroll
    for (int m = 32; m >= 1; m >>= 1) ss += __shfl_xor(ss, m);
    __shared__ float sb[2];
    if ((threadIdx.x & 63) == 0) sb[threadIdx.x >> 6] = ss;
    __syncthreads();
    float tot = sb[0] + sb[1];
    float sc = 1.f / fmaxf(sqrtf(tot), EPSF);
    vlad[idx] = v * sc;
    if (threadIdx.x == 0) atomicAdd(imgss + n, tot * sc * sc);
}

// projection: out[n][j] = (vladN[n] . proj_w[j]) / max(||vladN[n]||, eps) + b[j]
__global__ __launch_bounds__(256) void k_proj(
    const float* __restrict__ vlad, const float* __restrict__ pw,
    const float* __restrict__ pbias, const float* __restrict__ imgss,
    float* __restrict__ out)
{
    const int j = blockIdx.x;   // 0..127
    const int n = blockIdx.y;   // 0..31
    const int t = threadIdx.x;
    const float4* vp = (const float4*)(vlad + (size_t)n * (K_CL * C_CH));
    const float4* wp = (const float4*)(pw + (size_t)j * (K_CL * C_CH));
    float s = 0.f;
    #pragma unroll
    for (int r = 0; r < 8; ++r) {
        int i = t + 256 * r;
        float4 a = vp[i], b = wp[i];
        s += a.x * b.x + a.y * b.y + a.z * b.z + a.w * b.w;
    }
    #pragma unroll
    for (int m = 32; m >= 1; m >>= 1) s += __shfl_xor(s, m);
    __shared__ float sb[4];
    if ((t & 63) == 0) sb[t >> 6] = s;
    __syncthreads();
    if (t == 0) {
        float tot = sb[0] + sb[1] + sb[2] + sb[3];
        float inv = 1.f / fmaxf(sqrtf(imgss[n]), EPSF);
        out[n * C_CH + j] = tot * inv + pbias[j];
    }
}

extern "C" void kernel_launch(void* const* d_in, const int* in_sizes, int n_in,
                              void* d_out, int out_size, void* d_ws, size_t ws_size,
                              hipStream_t stream)
{
    const float* x      = (const float*)d_in[0];
    const float* conv_w = (const float*)d_in[1];
    const float* cent   = (const float*)d_in[2];
    const float* pw     = (const float*)d_in[3];
    const float* pbias  = (const float*)d_in[4];
    float* out = (float*)d_out;
    float* ws  = (float*)d_ws;

    float* vlad  = ws + WS_VLAD;
    float* asum  = ws + WS_ASUM;
    float* imgss = ws + WS_IMG;

    hipLaunchKernelGGL(k_zero, dim3((WS_TOT + 255) / 256), dim3(256), 0, stream, ws);
    hipLaunchKernelGGL(k_fused, dim3(N_IMG * (HW / TP)), dim3(TPB), 0, stream,
                       x, conv_w, vlad, asum);
    hipLaunchKernelGGL(k_rows, dim3(N_IMG * K_CL), dim3(C_CH), 0, stream,
                       vlad, asum, cent, imgss);
    hipLaunchKernelGGL(k_proj, dim3(C_CH, N_IMG), dim3(256), 0, stream,
                       vlad, pw, pbias, imgss, out);
}

// Round 3
// 154.798 us; speedup vs baseline: 1.9545x; 1.9545x over previous
//
#include <hip/hip_runtime.h>
#include <hip/hip_bf16.h>

typedef float f32x16 __attribute__((ext_vector_type(16)));
typedef short short8 __attribute__((ext_vector_type(8)));

#define N_IMG 32
#define C_CH  128
#define HW    9216
#define K_CL  64
#define EPSF  1e-12f

#define BPI   24      // blocks per image
#define PPB   384     // pixels per block
#define NIT   3       // iterations of 128 pixels

// ws layout (floats)
#define WS_VLAD 0
#define WS_ASUM (N_IMG*K_CL*C_CH)          // 262144
#define WS_IMG  (WS_ASUM + N_IMG*K_CL)     // 264192
#define WS_TOT  (WS_IMG + N_IMG)           // 264224

__device__ __forceinline__ unsigned short bfb(float f) {
    __hip_bfloat16 h = __float2bfloat16(f);   // RNE
    return *reinterpret_cast<unsigned short*>(&h);
}

__global__ void k_zero(float* __restrict__ ws) {
    int i = blockIdx.x * blockDim.x + threadIdx.x;
    if (i < WS_TOT) ws[i] = 0.f;
}

__global__ __launch_bounds__(256) void k_fused2(
    const float* __restrict__ x, const float* __restrict__ conv_w,
    float* __restrict__ vlad, float* __restrict__ asum)
{
    // all tiles: row pitch 256B, XOR swizzle addr ^= ((row&7)<<4)
    __shared__ __align__(16) char cw_lds[64 * 256];    // conv_w bf16 [64k][128c]
    __shared__ __align__(16) char x_lds [128 * 256];   // xn bf16 [128c][128p]
    __shared__ __align__(16) char s_lds [64 * 256];    // soft bf16 [64k][128p]

    const int t  = threadIdx.x;
    const int w  = t >> 6;          // wave 0..3
    const int l  = t & 63;
    const int lp = l & 31;
    const int h  = l >> 5;
    const int n    = blockIdx.x / BPI;
    const int pblk = (blockIdx.x % BPI) * PPB;

    // ---- stage conv_w -> bf16, swizzled ----
    #pragma unroll
    for (int r = 0; r < 16; ++r) {
        int e  = t + 256 * r;          // bf16-pair index 0..4095
        int k  = e >> 6;
        int c2 = (e & 63) << 1;
        unsigned pa = (unsigned)bfb(conv_w[k * C_CH + c2]) |
                      ((unsigned)bfb(conv_w[k * C_CH + c2 + 1]) << 16);
        int addr = (((k << 8) | (c2 << 1)) ^ ((k & 7) << 4));
        *reinterpret_cast<unsigned*>(cw_lds + addr) = pa;
    }
    __syncthreads();

    f32x16 va0, va1;
    #pragma unroll
    for (int r = 0; r < 16; ++r) { va0[r] = 0.f; va1[r] = 0.f; }
    float asac[2][16];
    #pragma unroll
    for (int r = 0; r < 16; ++r) { asac[0][r] = 0.f; asac[1][r] = 0.f; }

    const int p = w * 32 + lp;   // block-local pixel 0..127 (fixed per thread)

    for (int it = 0; it < NIT; ++it) {
        const int pix = pblk + it * 128 + p;
        const float* xp = x + (size_t)n * C_CH * HW + pix;

        // ---- load 64 channels for my pixel (c = 16s + 8h + i) ----
        float xv[8][8];
        #pragma unroll
        for (int s = 0; s < 8; ++s)
            #pragma unroll
            for (int i = 0; i < 8; ++i)
                xv[s][i] = xp[(size_t)(16 * s + 8 * h + i) * HW];

        // ---- in-register L2 normalize (partner lane l^32 has other c-half) ----
        float ss = 0.f;
        #pragma unroll
        for (int s = 0; s < 8; ++s)
            #pragma unroll
            for (int i = 0; i < 8; ++i) ss += xv[s][i] * xv[s][i];
        ss += __shfl_xor(ss, 32);
        const float scn = 1.f / fmaxf(sqrtf(ss), EPSF);

        // ---- xn as logits B-fragments (bf16) ----
        short8 xb[8];
        #pragma unroll
        for (int s = 0; s < 8; ++s)
            #pragma unroll
            for (int j = 0; j < 8; ++j)
                xb[s][j] = (short)bfb(xv[s][j] * scn);

        // ---- logits MFMA: [64k x 32p] per wave ----
        f32x16 d0, d1;
        #pragma unroll
        for (int r = 0; r < 16; ++r) { d0[r] = 0.f; d1[r] = 0.f; }
        #pragma unroll
        for (int s = 0; s < 8; ++s) {
            const int boff = (s << 5) | (h << 4);
            short8 a0 = *reinterpret_cast<const short8*>(
                cw_lds + ((((lp)      << 8) | boff) ^ ((lp & 7) << 4)));
            short8 a1 = *reinterpret_cast<const short8*>(
                cw_lds + ((((32 + lp) << 8) | boff) ^ ((lp & 7) << 4)));
            d0 = __builtin_amdgcn_mfma_f32_32x32x16_bf16(a0, xb[s], d0, 0, 0, 0);
            d1 = __builtin_amdgcn_mfma_f32_32x32x16_bf16(a1, xb[s], d1, 0, 0, 0);
        }

        // ---- lane-local softmax over 64 clusters for my pixel ----
        float m = d0[0];
        #pragma unroll
        for (int r = 1; r < 16; ++r) m = fmaxf(m, d0[r]);
        #pragma unroll
        for (int r = 0; r < 16; ++r) m = fmaxf(m, d1[r]);
        m = fmaxf(m, __shfl_xor(m, 32));
        float e0[16], e1[16], sm = 0.f;
        #pragma unroll
        for (int r = 0; r < 16; ++r) { e0[r] = __expf(d0[r] - m); sm += e0[r]; }
        #pragma unroll
        for (int r = 0; r < 16; ++r) { e1[r] = __expf(d1[r] - m); sm += e1[r]; }
        sm += __shfl_xor(sm, 32);
        const float inv = 1.f / sm;

        __syncthreads();   // prev iter's fragment reads done before overwrite

        // ---- soft -> s_lds [k][128p] bf16 swizzled; accumulate asum ----
        #pragma unroll
        for (int r = 0; r < 16; ++r) {
            const int kr = (r & 3) + 8 * (r >> 2) + 4 * h;
            float v0 = e0[r] * inv, v1 = e1[r] * inv;
            asac[0][r] += v0; asac[1][r] += v1;
            int a0 = (((kr)      << 8) | (p << 1)) ^ ((kr & 7) << 4);
            int a1 = (((32 + kr) << 8) | (p << 1)) ^ ((kr & 7) << 4);
            *reinterpret_cast<short*>(s_lds + a0) = (short)bfb(v0);
            *reinterpret_cast<short*>(s_lds + a1) = (short)bfb(v1);
        }
        // ---- xn -> x_lds [c][128p] bf16 swizzled ----
        #pragma unroll
        for (int s = 0; s < 8; ++s)
            #pragma unroll
            for (int j = 0; j < 8; ++j) {
                const int c = 16 * s + 8 * h + j;
                int a = ((c << 8) | (p << 1)) ^ ((c & 7) << 4);
                *reinterpret_cast<short*>(x_lds + a) = (short)xb[s][j];
            }
        __syncthreads();

        // ---- VLAD MFMA: [64k x 32c] per wave, K = 128 pixels ----
        const int cB = 32 * w + lp;
        #pragma unroll
        for (int sp = 0; sp < 8; ++sp) {
            const int boff = (sp << 5) | (h << 4);
            short8 bf = *reinterpret_cast<const short8*>(
                x_lds + (((cB << 8) | boff) ^ ((cB & 7) << 4)));
            short8 s0 = *reinterpret_cast<const short8*>(
                s_lds + ((((lp)      << 8) | boff) ^ ((lp & 7) << 4)));
            short8 s1 = *reinterpret_cast<const short8*>(
                s_lds + ((((32 + lp) << 8) | boff) ^ ((lp & 7) << 4)));
            va0 = __builtin_amdgcn_mfma_f32_32x32x16_bf16(s0, bf, va0, 0, 0, 0);
            va1 = __builtin_amdgcn_mfma_f32_32x32x16_bf16(s1, bf, va1, 0, 0, 0);
        }
    }

    // ---- flush vlad partials ----
    float* vb = vlad + (size_t)n * K_CL * C_CH;
    const int cB = 32 * w + lp;
    #pragma unroll
    for (int r = 0; r < 16; ++r) {
        const int kr = (r & 3) + 8 * (r >> 2) + 4 * h;
        atomicAdd(vb + (kr)      * C_CH + cB, va0[r]);
        atomicAdd(vb + (32 + kr) * C_CH + cB, va1[r]);
    }
    // ---- flush asum (reduce over 32-lane half, 1 writer per half) ----
    #pragma unroll
    for (int tt = 0; tt < 2; ++tt)
        #pragma unroll
        for (int r = 0; r < 16; ++r) {
            float v = asac[tt][r];
            v += __shfl_xor(v, 1);
            v += __shfl_xor(v, 2);
            v += __shfl_xor(v, 4);
            v += __shfl_xor(v, 8);
            v += __shfl_xor(v, 16);
            if (lp == 0) {
                const int kr = 32 * tt + (r & 3) + 8 * (r >> 2) + 4 * h;
                atomicAdd(asum + n * K_CL + kr, v);
            }
        }
}

// per-(n,k) row: subtract asum*centroid, intra-normalize, accumulate image norm^2
__global__ void k_rows(float* __restrict__ vlad, const float* __restrict__ asum,
                       const float* __restrict__ cent, float* __restrict__ imgss)
{
    const int bx = blockIdx.x;            // n*64 + k
    const int n = bx >> 6, k = bx & 63;
    const int c = threadIdx.x;            // 128 threads
    float a = asum[n * K_CL + k];
    size_t idx = ((size_t)n * K_CL + k) * C_CH + c;
    float v = vlad[idx] - a * cent[k * C_CH + c];
    float ss = v * v;
    #pragma unroll
    for (int m = 32; m >= 1; m >>= 1) ss += __shfl_xor(ss, m);
    __shared__ float sb[2];
    if ((threadIdx.x & 63) == 0) sb[threadIdx.x >> 6] = ss;
    __syncthreads();
    float tot = sb[0] + sb[1];
    float sc = 1.f / fmaxf(sqrtf(tot), EPSF);
    vlad[idx] = v * sc;
    if (threadIdx.x == 0) atomicAdd(imgss + n, tot * sc * sc);
}

// projection with final L2 norm folded in
__global__ __launch_bounds__(256) void k_proj(
    const float* __restrict__ vlad, const float* __restrict__ pw,
    const float* __restrict__ pbias, const float* __restrict__ imgss,
    float* __restrict__ out)
{
    const int j = blockIdx.x;   // 0..127
    const int n = blockIdx.y;   // 0..31
    const int t = threadIdx.x;
    const float4* vp = (const float4*)(vlad + (size_t)n * (K_CL * C_CH));
    const float4* wp = (const float4*)(pw + (size_t)j * (K_CL * C_CH));
    float s = 0.f;
    #pragma unroll
    for (int r = 0; r < 8; ++r) {
        int i = t + 256 * r;
        float4 a = vp[i], b = wp[i];
        s += a.x * b.x + a.y * b.y + a.z * b.z + a.w * b.w;
    }
    #pragma unroll
    for (int m = 32; m >= 1; m >>= 1) s += __shfl_xor(s, m);
    __shared__ float sb[4];
    if ((t & 63) == 0) sb[t >> 6] = s;
    __syncthreads();
    if (t == 0) {
        float tot = sb[0] + sb[1] + sb[2] + sb[3];
        float inv = 1.f / fmaxf(sqrtf(imgss[n]), EPSF);
        out[n * C_CH + j] = tot * inv + pbias[j];
    }
}

extern "C" void kernel_launch(void* const* d_in, const int* in_sizes, int n_in,
                              void* d_out, int out_size, void* d_ws, size_t ws_size,
                              hipStream_t stream)
{
    const float* x      = (const float*)d_in[0];
    const float* conv_w = (const float*)d_in[1];
    const float* cent   = (const float*)d_in[2];
    const float* pw     = (const float*)d_in[3];
    const float* pbias  = (const float*)d_in[4];
    float* out = (float*)d_out;
    float* ws  = (float*)d_ws;

    float* vlad  = ws + WS_VLAD;
    float* asum  = ws + WS_ASUM;
    float* imgss = ws + WS_IMG;

    hipLaunchKernelGGL(k_zero, dim3((WS_TOT + 255) / 256), dim3(256), 0, stream, ws);
    hipLaunchKernelGGL(k_fused2, dim3(N_IMG * BPI), dim3(256), 0, stream,
                       x, conv_w, vlad, asum);
    hipLaunchKernelGGL(k_rows, dim3(N_IMG * K_CL), dim3(C_CH), 0, stream,
                       vlad, asum, cent, imgss);
    hipLaunchKernelGGL(k_proj, dim3(C_CH, N_IMG), dim3(256), 0, stream,
                       vlad, pw, pbias, imgss, out);
}

// Round 4
// 124.487 us; speedup vs baseline: 2.4304x; 1.2435x over previous
//
#include <hip/hip_runtime.h>
#include <hip/hip_bf16.h>

typedef float f32x16 __attribute__((ext_vector_type(16)));
typedef short short8 __attribute__((ext_vector_type(8)));

#define N_IMG 32
#define C_CH  128
#define HW    9216
#define K_CL  64
#define EPSF  1e-12f

#define BPI   24      // blocks per image
#define PPB   384     // pixels per block
#define NIT   3       // iterations of 128 pixels

// ws layout (floats)
#define WS_VLAD 0
#define WS_ASUM (N_IMG*K_CL*C_CH)              // 262144
#define WS_IMG  (WS_ASUM + N_IMG*K_CL)         // 264192
#define WS_ZERO (WS_IMG + N_IMG)               // 264224 (zeroed prefix)
#define WS_PART WS_ZERO
#define NPART   (N_IMG*BPI)                    // 768
#define WS_ASP  (WS_PART + NPART*K_CL*C_CH)    // + 6291456
#define WS_STORE_TOT (WS_ASP + NPART*K_CL)     // 6604832 floats

__device__ __forceinline__ unsigned short bfb(float f) {
    __hip_bfloat16 h = __float2bfloat16(f);   // RNE
    return *reinterpret_cast<unsigned short*>(&h);
}

__global__ void k_zero(float* __restrict__ ws) {
    int i = blockIdx.x * blockDim.x + threadIdx.x;
    if (i < WS_ZERO) ws[i] = 0.f;
}

__global__ __launch_bounds__(256) void k_fused2(
    const float* __restrict__ x, const float* __restrict__ conv_w,
    float* __restrict__ vlad, float* __restrict__ asum,
    float* __restrict__ part, float* __restrict__ aspart, int use_part)
{
    // all tiles: row pitch 256B, XOR swizzle addr ^= ((row&7)<<4)
    __shared__ __align__(16) char cw_lds[64 * 256];    // conv_w bf16 [64k][128c]
    __shared__ __align__(16) char x_lds [128 * 256];   // xn bf16 [128c][128p]
    __shared__ __align__(16) char s_lds [64 * 256];    // soft bf16 [64k][128p]

    const int t  = threadIdx.x;
    const int w  = t >> 6;          // wave 0..3
    const int l  = t & 63;
    const int lp = l & 31;
    const int h  = l >> 5;
    const int n    = blockIdx.x / BPI;
    const int pblk = (blockIdx.x % BPI) * PPB;

    // ---- stage conv_w -> bf16, swizzled ----
    #pragma unroll
    for (int r = 0; r < 16; ++r) {
        int e  = t + 256 * r;          // bf16-pair index 0..4095
        int k  = e >> 6;
        int c2 = (e & 63) << 1;
        unsigned pa = (unsigned)bfb(conv_w[k * C_CH + c2]) |
                      ((unsigned)bfb(conv_w[k * C_CH + c2 + 1]) << 16);
        int addr = (((k << 8) | (c2 << 1)) ^ ((k & 7) << 4));
        *reinterpret_cast<unsigned*>(cw_lds + addr) = pa;
    }
    __syncthreads();

    f32x16 va0, va1;
    #pragma unroll
    for (int r = 0; r < 16; ++r) { va0[r] = 0.f; va1[r] = 0.f; }
    float asac[2][16];
    #pragma unroll
    for (int r = 0; r < 16; ++r) { asac[0][r] = 0.f; asac[1][r] = 0.f; }

    const int p = w * 32 + lp;   // block-local pixel 0..127 (fixed per thread)
    const float* xbase = x + (size_t)n * C_CH * HW;

    // ---- prologue: load it=0's 64 channels for my pixel ----
    float xv[8][8];
    {
        const float* xp = xbase + pblk + p;
        #pragma unroll
        for (int s = 0; s < 8; ++s)
            #pragma unroll
            for (int i = 0; i < 8; ++i)
                xv[s][i] = xp[(size_t)(16 * s + 8 * h + i) * HW];
    }

    for (int it = 0; it < NIT; ++it) {
        // ---- in-register L2 normalize (partner lane l^32 has other c-half) ----
        float ss = 0.f;
        #pragma unroll
        for (int s = 0; s < 8; ++s)
            #pragma unroll
            for (int i = 0; i < 8; ++i) ss += xv[s][i] * xv[s][i];
        ss += __shfl_xor(ss, 32);
        const float scn = 1.f / fmaxf(sqrtf(ss), EPSF);

        // ---- xn as logits B-fragments (bf16) ----
        short8 xb[8];
        #pragma unroll
        for (int s = 0; s < 8; ++s)
            #pragma unroll
            for (int j = 0; j < 8; ++j)
                xb[s][j] = (short)bfb(xv[s][j] * scn);

        // ---- prefetch next iteration's x (covered by MFMA/softmax below) ----
        if (it + 1 < NIT) {
            const float* xp = xbase + pblk + (it + 1) * 128 + p;
            #pragma unroll
            for (int s = 0; s < 8; ++s)
                #pragma unroll
                for (int i = 0; i < 8; ++i)
                    xv[s][i] = xp[(size_t)(16 * s + 8 * h + i) * HW];
        }

        // ---- logits MFMA: [64k x 32p] per wave ----
        f32x16 d0, d1;
        #pragma unroll
        for (int r = 0; r < 16; ++r) { d0[r] = 0.f; d1[r] = 0.f; }
        #pragma unroll
        for (int s = 0; s < 8; ++s) {
            const int boff = (s << 5) | (h << 4);
            short8 a0 = *reinterpret_cast<const short8*>(
                cw_lds + ((((lp)      << 8) | boff) ^ ((lp & 7) << 4)));
            short8 a1 = *reinterpret_cast<const short8*>(
                cw_lds + ((((32 + lp) << 8) | boff) ^ ((lp & 7) << 4)));
            d0 = __builtin_amdgcn_mfma_f32_32x32x16_bf16(a0, xb[s], d0, 0, 0, 0);
            d1 = __builtin_amdgcn_mfma_f32_32x32x16_bf16(a1, xb[s], d1, 0, 0, 0);
        }

        // ---- lane-local softmax over 64 clusters for my pixel ----
        float m = d0[0];
        #pragma unroll
        for (int r = 1; r < 16; ++r) m = fmaxf(m, d0[r]);
        #pragma unroll
        for (int r = 0; r < 16; ++r) m = fmaxf(m, d1[r]);
        m = fmaxf(m, __shfl_xor(m, 32));
        float e0[16], e1[16], sm = 0.f;
        #pragma unroll
        for (int r = 0; r < 16; ++r) { e0[r] = __expf(d0[r] - m); sm += e0[r]; }
        #pragma unroll
        for (int r = 0; r < 16; ++r) { e1[r] = __expf(d1[r] - m); sm += e1[r]; }
        sm += __shfl_xor(sm, 32);
        const float inv = 1.f / sm;

        __syncthreads();   // prev iter's fragment reads done before overwrite

        // ---- soft -> s_lds [k][128p] bf16 swizzled; accumulate asum ----
        #pragma unroll
        for (int r = 0; r < 16; ++r) {
            const int kr = (r & 3) + 8 * (r >> 2) + 4 * h;
            float v0 = e0[r] * inv, v1 = e1[r] * inv;
            asac[0][r] += v0; asac[1][r] += v1;
            int a0 = (((kr)      << 8) | (p << 1)) ^ ((kr & 7) << 4);
            int a1 = (((32 + kr) << 8) | (p << 1)) ^ ((kr & 7) << 4);
            *reinterpret_cast<short*>(s_lds + a0) = (short)bfb(v0);
            *reinterpret_cast<short*>(s_lds + a1) = (short)bfb(v1);
        }
        // ---- xn -> x_lds [c][128p] bf16 swizzled ----
        #pragma unroll
        for (int s = 0; s < 8; ++s)
            #pragma unroll
            for (int j = 0; j < 8; ++j) {
                const int c = 16 * s + 8 * h + j;
                int a = ((c << 8) | (p << 1)) ^ ((c & 7) << 4);
                *reinterpret_cast<short*>(x_lds + a) = (short)xb[s][j];
            }
        __syncthreads();

        // ---- VLAD MFMA: [64k x 32c] per wave, K = 128 pixels ----
        const int cB = 32 * w + lp;
        #pragma unroll
        for (int sp = 0; sp < 8; ++sp) {
            const int boff = (sp << 5) | (h << 4);
            short8 bf = *reinterpret_cast<const short8*>(
                x_lds + (((cB << 8) | boff) ^ ((cB & 7) << 4)));
            short8 s0 = *reinterpret_cast<const short8*>(
                s_lds + ((((lp)      << 8) | boff) ^ ((lp & 7) << 4)));
            short8 s1 = *reinterpret_cast<const short8*>(
                s_lds + ((((32 + lp) << 8) | boff) ^ ((lp & 7) << 4)));
            va0 = __builtin_amdgcn_mfma_f32_32x32x16_bf16(s0, bf, va0, 0, 0, 0);
            va1 = __builtin_amdgcn_mfma_f32_32x32x16_bf16(s1, bf, va1, 0, 0, 0);
        }
    }

    // ---- flush partials ----
    const int cB = 32 * w + lp;
    if (use_part) {
        // plain coalesced stores of this block's partial tile
        float* pb_ = part + (size_t)blockIdx.x * (K_CL * C_CH) + cB;
        #pragma unroll
        for (int r = 0; r < 16; ++r) {
            const int kr = (r & 3) + 8 * (r >> 2) + 4 * h;
            pb_[(kr)      * C_CH] = va0[r];
            pb_[(32 + kr) * C_CH] = va1[r];
        }
        #pragma unroll
        for (int tt = 0; tt < 2; ++tt)
            #pragma unroll
            for (int r = 0; r < 16; ++r) {
                float v = asac[tt][r];
                v += __shfl_xor(v, 1);
                v += __shfl_xor(v, 2);
                v += __shfl_xor(v, 4);
                v += __shfl_xor(v, 8);
                v += __shfl_xor(v, 16);
                if (lp == 0) {
                    const int kr = 32 * tt + (r & 3) + 8 * (r >> 2) + 4 * h;
                    aspart[blockIdx.x * K_CL + kr] = v;
                }
            }
    } else {
        float* vb = vlad + (size_t)n * K_CL * C_CH;
        #pragma unroll
        for (int r = 0; r < 16; ++r) {
            const int kr = (r & 3) + 8 * (r >> 2) + 4 * h;
            atomicAdd(vb + (kr)      * C_CH + cB, va0[r]);
            atomicAdd(vb + (32 + kr) * C_CH + cB, va1[r]);
        }
        #pragma unroll
        for (int tt = 0; tt < 2; ++tt)
            #pragma unroll
            for (int r = 0; r < 16; ++r) {
                float v = asac[tt][r];
                v += __shfl_xor(v, 1);
                v += __shfl_xor(v, 2);
                v += __shfl_xor(v, 4);
                v += __shfl_xor(v, 8);
                v += __shfl_xor(v, 16);
                if (lp == 0) {
                    const int kr = 32 * tt + (r & 3) + 8 * (r >> 2) + 4 * h;
                    atomicAdd(asum + n * K_CL + kr, v);
                }
            }
    }
}

// store-path reducer: sum 24 block partials, subtract asum*centroid, normalize
__global__ void k_rows_part(float* __restrict__ vlad, const float* __restrict__ part,
                            const float* __restrict__ aspart,
                            const float* __restrict__ cent, float* __restrict__ imgss)
{
    const int bx = blockIdx.x;            // n*64 + k
    const int n = bx >> 6, k = bx & 63;
    const int c = threadIdx.x;            // 128 threads
    const int b0 = n * BPI;
    float v = 0.f, a = 0.f;
    #pragma unroll
    for (int b = 0; b < BPI; ++b) {
        v += part[(size_t)(b0 + b) * (K_CL * C_CH) + k * C_CH + c];
        a += aspart[(b0 + b) * K_CL + k];
    }
    v -= a * cent[k * C_CH + c];
    float ssq = v * v;
    #pragma unroll
    for (int m = 32; m >= 1; m >>= 1) ssq += __shfl_xor(ssq, m);
    __shared__ float sb[2];
    if ((threadIdx.x & 63) == 0) sb[threadIdx.x >> 6] = ssq;
    __syncthreads();
    float tot = sb[0] + sb[1];
    float sc = 1.f / fmaxf(sqrtf(tot), EPSF);
    vlad[((size_t)n * K_CL + k) * C_CH + c] = v * sc;
    if (threadIdx.x == 0) atomicAdd(imgss + n, tot * sc * sc);
}

// atomic-path reducer (fallback)
__global__ void k_rows(float* __restrict__ vlad, const float* __restrict__ asum,
                       const float* __restrict__ cent, float* __restrict__ imgss)
{
    const int bx = blockIdx.x;            // n*64 + k
    const int n = bx >> 6, k = bx & 63;
    const int c = threadIdx.x;            // 128 threads
    float a = asum[n * K_CL + k];
    size_t idx = ((size_t)n * K_CL + k) * C_CH + c;
    float v = vlad[idx] - a * cent[k * C_CH + c];
    float ssq = v * v;
    #pragma unroll
    for (int m = 32; m >= 1; m >>= 1) ssq += __shfl_xor(ssq, m);
    __shared__ float sb[2];
    if ((threadIdx.x & 63) == 0) sb[threadIdx.x >> 6] = ssq;
    __syncthreads();
    float tot = sb[0] + sb[1];
    float sc = 1.f / fmaxf(sqrtf(tot), EPSF);
    vlad[idx] = v * sc;
    if (threadIdx.x == 0) atomicAdd(imgss + n, tot * sc * sc);
}

// projection with final L2 norm folded in
__global__ __launch_bounds__(256) void k_proj(
    const float* __restrict__ vlad, const float* __restrict__ pw,
    const float* __restrict__ pbias, const float* __restrict__ imgss,
    float* __restrict__ out)
{
    const int j = blockIdx.x;   // 0..127
    const int n = blockIdx.y;   // 0..31
    const int t = threadIdx.x;
    const float4* vp = (const float4*)(vlad + (size_t)n * (K_CL * C_CH));
    const float4* wp = (const float4*)(pw + (size_t)j * (K_CL * C_CH));
    float s = 0.f;
    #pragma unroll
    for (int r = 0; r < 8; ++r) {
        int i = t + 256 * r;
        float4 a = vp[i], b = wp[i];
        s += a.x * b.x + a.y * b.y + a.z * b.z + a.w * b.w;
    }
    #pragma unroll
    for (int m = 32; m >= 1; m >>= 1) s += __shfl_xor(s, m);
    __shared__ float sb[4];
    if ((t & 63) == 0) sb[t >> 6] = s;
    __syncthreads();
    if (t == 0) {
        float tot = sb[0] + sb[1] + sb[2] + sb[3];
        float inv = 1.f / fmaxf(sqrtf(imgss[n]), EPSF);
        out[n * C_CH + j] = tot * inv + pbias[j];
    }
}

extern "C" void kernel_launch(void* const* d_in, const int* in_sizes, int n_in,
                              void* d_out, int out_size, void* d_ws, size_t ws_size,
                              hipStream_t stream)
{
    const float* x      = (const float*)d_in[0];
    const float* conv_w = (const float*)d_in[1];
    const float* cent   = (const float*)d_in[2];
    const float* pw     = (const float*)d_in[3];
    const float* pbias  = (const float*)d_in[4];
    float* out = (float*)d_out;
    float* ws  = (float*)d_ws;

    float* vlad   = ws + WS_VLAD;
    float* asum   = ws + WS_ASUM;
    float* imgss  = ws + WS_IMG;
    float* part   = ws + WS_PART;
    float* aspart = ws + WS_ASP;

    const int use_part = (ws_size >= (size_t)WS_STORE_TOT * sizeof(float)) ? 1 : 0;

    hipLaunchKernelGGL(k_zero, dim3((WS_ZERO + 255) / 256), dim3(256), 0, stream, ws);
    hipLaunchKernelGGL(k_fused2, dim3(N_IMG * BPI), dim3(256), 0, stream,
                       x, conv_w, vlad, asum, part, aspart, use_part);
    if (use_part) {
        hipLaunchKernelGGL(k_rows_part, dim3(N_IMG * K_CL), dim3(C_CH), 0, stream,
                           vlad, part, aspart, cent, imgss);
    } else {
        hipLaunchKernelGGL(k_rows, dim3(N_IMG * K_CL), dim3(C_CH), 0, stream,
                           vlad, asum, cent, imgss);
    }
    hipLaunchKernelGGL(k_proj, dim3(C_CH, N_IMG), dim3(256), 0, stream,
                       vlad, pw, pbias, imgss, out);
}